// Round 2
// baseline (335.400 us; speedup 1.0000x reference)
//
#include <hip/hip_runtime.h>

// Layouts: all intermediates FEATURE-MAJOR: h[b][f][n], n in [0,4096) = 64x64 grid.
// GNN layer exact rewrite: h' = relu( agg(h) @ W + rowsum*b ),
//   agg(h)[n] = sum_{nb} h[nb] / (deg(n)+1e-6),  rowsum(n) = deg/(deg+1e-6).
//
// R1: wave = 64 nodes (lane=m), each wave owns 32 features. B operand comes
// from SGPRs (wave-uniform s_load), A from 1x ds_read_b32/kk. This removes the
// LDS-throughput bottleneck seen in R0 (VALUBusy 30%, 3x b128/32FMA).

#define RFL(x) __builtin_amdgcn_readfirstlane(x)

__global__ void zero_kernel(float* __restrict__ p) {
    p[blockIdx.x * 256 + threadIdx.x] = 0.f;
}

// ---------------- embed: h0[b][d][n], thread-per-node, weights via SGPR ----------------
__global__ __launch_bounds__(256) void embed_kernel(
    const float* __restrict__ obs, const float* __restrict__ e1w,
    const float* __restrict__ e1b, const float* __restrict__ e2w,
    const float* __restrict__ e2b, float* __restrict__ h0)
{
    const int tid = threadIdx.x;
    const int gid = blockIdx.x * 256 + tid;
    const int b = gid >> 12;
    const int n = gid & 4095;
    const float* ob = obs + ((size_t)b << 16) + n;   // obs[b][c][n]

    float x[16];
#pragma unroll
    for (int c = 0; c < 16; c++) x[c] = ob[(size_t)c << 12];

    float h[64];
#pragma unroll
    for (int d = 0; d < 64; d++) h[d] = e1b[d];            // uniform -> s_load
#pragma unroll
    for (int c = 0; c < 16; c++) {
        const float xv = x[c];
#pragma unroll
        for (int d = 0; d < 64; d++) h[d] = fmaf(xv, e1w[c * 64 + d], h[d]);
    }
#pragma unroll
    for (int d = 0; d < 64; d++) h[d] = fmaxf(h[d], 0.f);

    float o[64];
#pragma unroll
    for (int d = 0; d < 64; d++) o[d] = e2b[d];
#pragma unroll
    for (int k = 0; k < 64; k++) {
        const float hv = h[k];
#pragma unroll
        for (int d = 0; d < 64; d++) o[d] = fmaf(hv, e2w[k * 64 + d], o[d]);
    }
    float* hp = h0 + ((size_t)b << 18) + n;   // h0[b][d][n]
#pragma unroll
    for (int d = 0; d < 64; d++) hp[(size_t)d << 12] = fmaxf(o[d], 0.f);
}

// ---------------- GNN layer: block = (b, image row); lane=node, wave=32 feats ----------------
template <int K, bool MEAN>
__global__ __launch_bounds__(256, 4) void gnn_kernel(
    const float* __restrict__ hin, const float* __restrict__ W,
    const float* __restrict__ bias, float* __restrict__ hout,
    float* __restrict__ gsum)
{
    // A-tile: K*64 floats. MEAN also needs a 128x65 transpose buffer (aliased).
    constexpr int SMSZ = MEAN ? (128 * 65) : (K * 64);
    __shared__ float smem[SMSZ];

    const int tid = threadIdx.x;
    const int b = blockIdx.x >> 6;
    const int row = blockIdx.x & 63;
    const int lane = tid & 63;                 // node m within the row
    const int wave = RFL(tid >> 6);            // 0..3, forced wave-uniform
    const float* hb = hin + (size_t)b * K * 4096 + row * 64;

    // ---- stage aggregated A[K][64] (whole K depth, one barrier) ----
#pragma unroll 8
    for (int jj = 0; jj < K / 4; jj++) {
        const int e = tid + 256 * jj;
        const int kk = e >> 6;
        const int m = e & 63;
        const float* hk = hb + ((size_t)kk << 12);
        float s = 0.f;
        if (row > 0)  s += hk[m - 64];
        if (row < 63) s += hk[m + 64];
        if (m > 0)    s += hk[m - 1];
        if (m < 63)   s += hk[m + 1];
        const int deg = (row > 0) + (row < 63) + (m > 0) + (m < 63);
        smem[kk * 64 + m] = s * (1.f / ((float)deg + 1e-6f));
    }
    __syncthreads();

    // ---- main loop: 1 ds_read_b32 + 32 sgpr-operand FMA per kk ----
    const int f0 = wave * 32;
    float acc[32];
#pragma unroll
    for (int j = 0; j < 32; j++) acc[j] = 0.f;

#pragma unroll 8
    for (int kk = 0; kk < K; kk++) {
        const float a = smem[kk * 64 + lane];
        const float* wp = W + kk * 128 + f0;   // wave-uniform -> s_load_dwordx16 x2
#pragma unroll
        for (int j = 0; j < 32; j++) acc[j] = fmaf(a, wp[j], acc[j]);
    }

    // ---- epilogue: + rowsum*bias, relu ----
    const int m = lane;
    const int degm = (row > 0) + (row < 63) + (m > 0) + (m < 63);
    const float rs = (float)degm / ((float)degm + 1e-6f);
    const float* bp = bias + f0;               // wave-uniform
    float v[32];
#pragma unroll
    for (int j = 0; j < 32; j++) v[j] = fmaxf(fmaf(rs, bp[j], acc[j]), 0.f);

    if (!MEAN) {
        float* op = hout + ((size_t)b * 128 + f0) * 4096 + row * 64 + m;
#pragma unroll
        for (int j = 0; j < 32; j++) op[(size_t)j * 4096] = v[j];
    } else {
        __syncthreads();   // A-tile reads done in ALL waves before aliasing smem
        // transpose to [f][m] with pad-65 (conflict-free writes & reads)
#pragma unroll
        for (int j = 0; j < 32; j++) smem[(f0 + j) * 65 + m] = v[j];
        __syncthreads();
        const int f = tid & 127;
        const int seg = tid >> 7;              // 0 or 1: halves of the 64 nodes
        float s = 0.f;
#pragma unroll
        for (int j = 0; j < 32; j++) s += smem[f * 65 + seg * 32 + j];
        atomicAdd(&gsum[b * 128 + f], s * (1.f / 4096.f));
    }
}

// ---------------- readout: per-batch block, 2-layer MLP ----------------
__global__ __launch_bounds__(256) void readout_kernel(
    const float* __restrict__ gsum, const float* __restrict__ r1w,
    const float* __restrict__ r1b, const float* __restrict__ r2w,
    const float* __restrict__ r2b, float* __restrict__ out)
{
    __shared__ float gs[128];
    __shared__ float g2[256];
    const int b = blockIdx.x;
    const int tid = threadIdx.x;
    if (tid < 128) gs[tid] = gsum[b * 128 + tid];
    __syncthreads();
    float a = r1b[tid];
#pragma unroll 8
    for (int k = 0; k < 128; k++) a = fmaf(gs[k], r1w[k * 256 + tid], a);
    g2[tid] = fmaxf(a, 0.f);
    __syncthreads();
    float a2 = r2b[tid];
#pragma unroll 8
    for (int k = 0; k < 256; k++) a2 = fmaf(g2[k], r2w[k * 256 + tid], a2);
    out[b * 256 + tid] = fmaxf(a2, 0.f);
}

extern "C" void kernel_launch(void* const* d_in, const int* in_sizes, int n_in,
                              void* d_out, int out_size, void* d_ws, size_t ws_size,
                              hipStream_t stream)
{
    const float* obs = (const float*)d_in[0];
    const float* e1w = (const float*)d_in[1];
    const float* e1b = (const float*)d_in[2];
    const float* e2w = (const float*)d_in[3];
    const float* e2b = (const float*)d_in[4];
    const float* g1w = (const float*)d_in[5];
    const float* g1b = (const float*)d_in[6];
    const float* g2w = (const float*)d_in[7];
    const float* g2b = (const float*)d_in[8];
    const float* g3w = (const float*)d_in[9];
    const float* g3b = (const float*)d_in[10];
    const float* r1w = (const float*)d_in[11];
    const float* r1b = (const float*)d_in[12];
    const float* r2w = (const float*)d_in[13];
    const float* r2b = (const float*)d_in[14];
    float* out = (float*)d_out;
    float* ws = (float*)d_ws;

    float* h0 = ws;                                 // 16 MB
    float* h1 = ws + 4194304;                       // 32 MB
    float* h2 = ws + 4194304 + 8388608;             // 32 MB
    float* gsum = ws + 4194304 + 2 * 8388608;       // 2048 floats

    hipLaunchKernelGGL(zero_kernel, dim3(8), dim3(256), 0, stream, gsum);
    hipLaunchKernelGGL(embed_kernel, dim3(256), dim3(256), 0, stream,
                       obs, e1w, e1b, e2w, e2b, h0);
    hipLaunchKernelGGL((gnn_kernel<64, false>), dim3(1024), dim3(256), 0, stream,
                       h0, g1w, g1b, h1, nullptr);
    hipLaunchKernelGGL((gnn_kernel<128, false>), dim3(1024), dim3(256), 0, stream,
                       h1, g2w, g2b, h2, nullptr);
    hipLaunchKernelGGL((gnn_kernel<128, true>), dim3(1024), dim3(256), 0, stream,
                       h2, g3w, g3b, nullptr, gsum);
    hipLaunchKernelGGL(readout_kernel, dim3(16), dim3(256), 0, stream,
                       gsum, r1w, r1b, r2w, r2b, out);
}

// Round 3
// 222.484 us; speedup vs baseline: 1.5075x; 1.5075x over previous
//
#include <hip/hip_runtime.h>

// MFMA bf16x3 implementation. All intermediates FEATURE-MAJOR h[b][f][n], n = 64x64 grid.
// GNN layer exact rewrite: h' = relu( agg(h) @ W + rowsum*b ).
// Every fp32 operand is split a = hi + lo (bf16 RNE); product uses 3 MFMAs:
// hi*whi + hi*wlo + lo*whi, fp32 accumulate -> ~2^-17 relative error.
//
// MFMA 16x16x32 bf16 layouts (verified, learn_hip m89/m120):
//   A-operand (MxK): m = lane&15, k = (lane>>4)*8 + j   (j = 0..7, one b128)
//   B-operand (KxN): n = lane&15, k = (lane>>4)*8 + j
//   C/D:             col(N) = lane&15, row(M) = (lane>>4)*4 + reg
// We put W in the A slot (M=feats) and agg-nodes in the B slot (N=nodes), so
// C cols = nodes -> stores are 16-dword segments (semi-coalesced), no transpose.

typedef __attribute__((ext_vector_type(8))) short bf16x8;
typedef __attribute__((ext_vector_type(4))) float f32x4;
#define MFMA(a, b, c) __builtin_amdgcn_mfma_f32_16x16x32_bf16(a, b, c, 0, 0, 0)

__device__ inline ushort bf16h(float x) {
    unsigned u = __float_as_uint(x);
    return (ushort)((u + 0x7fffu + ((u >> 16) & 1u)) >> 16);
}
__device__ inline void split_bf16(float x, ushort& hi, ushort& lo) {
    hi = bf16h(x);
    lo = bf16h(x - __uint_as_float(((unsigned)hi) << 16));
}

__global__ void zero_kernel(float* __restrict__ p) {
    p[blockIdx.x * 256 + threadIdx.x] = 0.f;
}

// ---- weight pre-split into fragment-ordered bf16 hi/lo planes --------------
// Unit (kc,t) = 2 planes x 512 ushorts (1024 B each). Per layer, unit index = kc*T + t.
// ws ushort offsets: e1@0 (4 units), e2@4096 (8), g1@12288 (16), g2@28672 (32), g3@61440 (32).
__global__ __launch_bounds__(64) void wprep_kernel(
    const float* __restrict__ e1w, const float* __restrict__ e2w,
    const float* __restrict__ g1w, const float* __restrict__ g2w,
    const float* __restrict__ g3w, ushort* __restrict__ wf)
{
    const int blk = blockIdx.x, l = threadIdx.x;
    const float* src; int K, N, kc, t; ushort* dst;
    if (blk < 4)        { src = e1w; K = 16;  N = 64;  kc = 0; t = blk;      dst = wf; }
    else if (blk < 12)  { src = e2w; K = 64;  N = 64;  int u = blk - 4;  kc = u >> 2; t = u & 3; dst = wf + 4096; }
    else if (blk < 28)  { src = g1w; K = 64;  N = 128; int u = blk - 12; kc = u >> 3; t = u & 7; dst = wf + 12288; }
    else if (blk < 60)  { src = g2w; K = 128; N = 128; int u = blk - 28; kc = u >> 3; t = u & 7; dst = wf + 28672; }
    else                { src = g3w; K = 128; N = 128; int u = blk - 60; kc = u >> 3; t = u & 7; dst = wf + 61440; }
    const int T = (N == 64) ? 4 : 8;
    ushort* uh = dst + ((kc * T + t) * 2 + 0) * 512 + l * 8;
    ushort* ul = dst + ((kc * T + t) * 2 + 1) * 512 + l * 8;
    const int f = t * 16 + (l & 15);
    const int kb = kc * 32 + ((l >> 4) << 3);
#pragma unroll
    for (int j = 0; j < 8; j++) {
        const int k = kb + j;
        const float w = (k < K) ? src[k * N + f] : 0.f;
        ushort hi, lo; split_bf16(w, hi, lo);
        uh[j] = hi; ul[j] = lo;
    }
}

// ---- embed: fused 2-layer MLP via MFMA, block = (b, image row) = 64 nodes ----
__global__ __launch_bounds__(256, 4) void embed_kernel(
    const float* __restrict__ obs, const ushort* __restrict__ wf,
    const float* __restrict__ e1b, const float* __restrict__ e2b,
    float* __restrict__ h0)
{
    __shared__ __align__(16) ushort lds[4096 + 8192]; // x-frags (K=32 padded) + h1-frags (K=64)
    const int tid = threadIdx.x, b = blockIdx.x >> 6, row = blockIdx.x & 63;
    const int lane = tid & 63, w = tid >> 6, quad = lane >> 4, nl = lane & 15;

    // stage x as B-operand frags (zeros for k>=16)
#pragma unroll
    for (int it = 0; it < 8; it++) {
        const int e = tid + 256 * it;               // 2048 = 32k x 64n
        const int kk = e >> 6, n = e & 63;
        const float v = (kk < 16) ? obs[((size_t)(b * 16 + kk) << 12) + row * 64 + n] : 0.f;
        ushort hi, lo; split_bf16(v, hi, lo);
        const int nt = n >> 4, q2 = (kk >> 3) & 3, j = kk & 7;
        ushort* p = lds + (nt * 2) * 512 + (q2 * 16 + (n & 15)) * 8 + j;
        p[0] = hi; p[512] = lo;
    }
    __syncthreads();

    // layer 1: wave w -> mid-feats 16w..16w+15 (t = w)
    const bf16x8 wh = *(const bf16x8*)(wf + (w * 2) * 512 + lane * 8);
    const bf16x8 wl = *(const bf16x8*)(wf + (w * 2 + 1) * 512 + lane * 8);
    f32x4 a1[4];
#pragma unroll
    for (int nt = 0; nt < 4; nt++) {
        const ushort* bb = lds + (nt * 2) * 512 + lane * 8;
        const bf16x8 bh = *(const bf16x8*)bb;
        const bf16x8 bl = *(const bf16x8*)(bb + 512);
        f32x4 c = {0.f, 0.f, 0.f, 0.f};
        c = MFMA(wh, bh, c); c = MFMA(wh, bl, c); c = MFMA(wl, bh, c);
        a1[nt] = c;
    }
    // bias+relu, write as layer-2 B-operand frags
    ushort* h1f = lds + 4096;
#pragma unroll
    for (int reg = 0; reg < 4; reg++) {
        const int fm = 16 * w + quad * 4 + reg;     // layer-2 k index
        const float bv = e1b[fm];
        const int kc2 = fm >> 5, q2 = (fm >> 3) & 3, j2 = fm & 7;
#pragma unroll
        for (int nt = 0; nt < 4; nt++) {
            const int n = 16 * nt + nl;
            const float v = fmaxf(a1[nt][reg] + bv, 0.f);
            ushort hi, lo; split_bf16(v, hi, lo);
            ushort* p = h1f + ((nt * 2 + kc2) * 2) * 512 + (q2 * 16 + (n & 15)) * 8 + j2;
            p[0] = hi; p[512] = lo;
        }
    }
    __syncthreads();

    // layer 2: K=64, out feats 16w..16w+15 (t = w)
    const ushort* e2f = wf + 4096;
    f32x4 a2[4];
#pragma unroll
    for (int nt = 0; nt < 4; nt++) a2[nt] = (f32x4){0.f, 0.f, 0.f, 0.f};
#pragma unroll
    for (int kc = 0; kc < 2; kc++) {
        const bf16x8 w2h = *(const bf16x8*)(e2f + ((kc * 4 + w) * 2) * 512 + lane * 8);
        const bf16x8 w2l = *(const bf16x8*)(e2f + ((kc * 4 + w) * 2 + 1) * 512 + lane * 8);
#pragma unroll
        for (int nt = 0; nt < 4; nt++) {
            const ushort* bb = h1f + ((nt * 2 + kc) * 2) * 512 + lane * 8;
            const bf16x8 bh = *(const bf16x8*)bb;
            const bf16x8 bl = *(const bf16x8*)(bb + 512);
            a2[nt] = MFMA(w2h, bh, a2[nt]);
            a2[nt] = MFMA(w2h, bl, a2[nt]);
            a2[nt] = MFMA(w2l, bh, a2[nt]);
        }
    }
#pragma unroll
    for (int reg = 0; reg < 4; reg++) {
        const int f = 16 * w + quad * 4 + reg;
        const float bv = e2b[f];
#pragma unroll
        for (int nt = 0; nt < 4; nt++) {
            const int n = 16 * nt + nl;
            h0[((size_t)(b * 64 + f) << 12) + row * 64 + n] = fmaxf(a2[nt][reg] + bv, 0.f);
        }
    }
}

// ---- GNN layer: block = (b, row), 64 nodes x 128 feats, MFMA bf16x3 ----
template <int K, bool MEAN>
__global__ __launch_bounds__(256, 4) void gnn_kernel(
    const float* __restrict__ hin, const ushort* __restrict__ wf,
    const float* __restrict__ bias, float* __restrict__ hout,
    float* __restrict__ gsum)
{
    constexpr int KC = K / 32;
    __shared__ __align__(16) ushort lds[KC * 4096]; // 4nt * KC * 2 planes * 512
    const int tid = threadIdx.x, b = blockIdx.x >> 6, row = blockIdx.x & 63;
    const int lane = tid & 63, w = tid >> 6, quad = lane >> 4, nl = lane & 15;
    const float* hb = hin + (size_t)b * K * 4096 + row * 64;

    // stage aggregated A (split) directly in B-operand fragment order
#pragma unroll 4
    for (int it = 0; it < K / 4; it++) {
        const int e = tid + 256 * it;
        const int kk = e >> 6, n = e & 63;
        const float* hk = hb + ((size_t)kk << 12);
        float s = 0.f;
        if (row > 0)  s += hk[n - 64];
        if (row < 63) s += hk[n + 64];
        if (n > 0)    s += hk[n - 1];
        if (n < 63)   s += hk[n + 1];
        const int deg = (row > 0) + (row < 63) + (n > 0) + (n < 63);
        const float a = s * (1.f / ((float)deg + 1e-6f));
        ushort hi, lo; split_bf16(a, hi, lo);
        const int nt = n >> 4, kc = kk >> 5, q2 = (kk >> 3) & 3, j = kk & 7;
        ushort* p = lds + ((nt * KC + kc) * 2) * 512 + (q2 * 16 + (n & 15)) * 8 + j;
        p[0] = hi; p[512] = lo;
    }
    __syncthreads();

    // main loop: wave w owns feat-tiles {2w, 2w+1}
    f32x4 acc[4][2];
#pragma unroll
    for (int nt = 0; nt < 4; nt++) { acc[nt][0] = (f32x4){0.f,0.f,0.f,0.f}; acc[nt][1] = (f32x4){0.f,0.f,0.f,0.f}; }
    const ushort* wfl = wf + lane * 8;
#pragma unroll
    for (int kc = 0; kc < KC; kc++) {
        const bf16x8 wh0 = *(const bf16x8*)(wfl + ((kc * 8 + 2 * w)     * 2)     * 512);
        const bf16x8 wl0 = *(const bf16x8*)(wfl + ((kc * 8 + 2 * w)     * 2 + 1) * 512);
        const bf16x8 wh1 = *(const bf16x8*)(wfl + ((kc * 8 + 2 * w + 1) * 2)     * 512);
        const bf16x8 wl1 = *(const bf16x8*)(wfl + ((kc * 8 + 2 * w + 1) * 2 + 1) * 512);
#pragma unroll
        for (int nt = 0; nt < 4; nt++) {
            const ushort* bb = lds + ((nt * KC + kc) * 2) * 512 + lane * 8;
            const bf16x8 bh = *(const bf16x8*)bb;
            const bf16x8 bl = *(const bf16x8*)(bb + 512);
            acc[nt][0] = MFMA(wh0, bh, acc[nt][0]);
            acc[nt][0] = MFMA(wh0, bl, acc[nt][0]);
            acc[nt][0] = MFMA(wl0, bh, acc[nt][0]);
            acc[nt][1] = MFMA(wh1, bh, acc[nt][1]);
            acc[nt][1] = MFMA(wh1, bl, acc[nt][1]);
            acc[nt][1] = MFMA(wl1, bh, acc[nt][1]);
        }
    }

    // epilogue: + rowsum*bias, relu
    if (!MEAN) {
#pragma unroll
        for (int ftl = 0; ftl < 2; ftl++) {
            const int fb = 32 * w + 16 * ftl + quad * 4;
            const float b0 = bias[fb], b1 = bias[fb + 1], b2 = bias[fb + 2], b3 = bias[fb + 3];
#pragma unroll
            for (int nt = 0; nt < 4; nt++) {
                const int n = 16 * nt + nl;
                const int deg = (row > 0) + (row < 63) + (n > 0) + (n < 63);
                const float rs = (float)deg / ((float)deg + 1e-6f);
                float* op = hout + ((size_t)(b * 128 + fb) << 12) + row * 64 + n;
                op[0]         = fmaxf(acc[nt][ftl][0] + rs * b0, 0.f);
                op[1u << 12]  = fmaxf(acc[nt][ftl][1] + rs * b1, 0.f);
                op[2u << 12]  = fmaxf(acc[nt][ftl][2] + rs * b2, 0.f);
                op[3u << 12]  = fmaxf(acc[nt][ftl][3] + rs * b3, 0.f);
            }
        }
    } else {
#pragma unroll
        for (int ftl = 0; ftl < 2; ftl++) {
            const int fb = 32 * w + 16 * ftl + quad * 4;
#pragma unroll
            for (int reg = 0; reg < 4; reg++) {
                const float bv = bias[fb + reg];
                float v = 0.f;
#pragma unroll
                for (int nt = 0; nt < 4; nt++) {
                    const int n = 16 * nt + nl;
                    const int deg = (row > 0) + (row < 63) + (n > 0) + (n < 63);
                    const float rs = (float)deg / ((float)deg + 1e-6f);
                    v += fmaxf(acc[nt][ftl][reg] + rs * bv, 0.f);
                }
                v += __shfl_xor(v, 1); v += __shfl_xor(v, 2);
                v += __shfl_xor(v, 4); v += __shfl_xor(v, 8);
                if (nl == 0) atomicAdd(&gsum[b * 128 + fb + reg], v * (1.f / 4096.f));
            }
        }
    }
}

// ---- readout: per-batch block, 2-layer MLP (fp32 vector) ----
__global__ __launch_bounds__(256) void readout_kernel(
    const float* __restrict__ gsum, const float* __restrict__ r1w,
    const float* __restrict__ r1b, const float* __restrict__ r2w,
    const float* __restrict__ r2b, float* __restrict__ out)
{
    __shared__ float gs[128];
    __shared__ float g2[256];
    const int b = blockIdx.x, tid = threadIdx.x;
    if (tid < 128) gs[tid] = gsum[b * 128 + tid];
    __syncthreads();
    float a = r1b[tid];
#pragma unroll 16
    for (int k = 0; k < 128; k++) a = fmaf(gs[k], r1w[k * 256 + tid], a);
    g2[tid] = fmaxf(a, 0.f);
    __syncthreads();
    float a2 = r2b[tid];
#pragma unroll 16
    for (int k = 0; k < 256; k++) a2 = fmaf(g2[k], r2w[k * 256 + tid], a2);
    out[b * 256 + tid] = fmaxf(a2, 0.f);
}

extern "C" void kernel_launch(void* const* d_in, const int* in_sizes, int n_in,
                              void* d_out, int out_size, void* d_ws, size_t ws_size,
                              hipStream_t stream)
{
    const float* obs = (const float*)d_in[0];
    const float* e1w = (const float*)d_in[1];
    const float* e1b = (const float*)d_in[2];
    const float* e2w = (const float*)d_in[3];
    const float* e2b = (const float*)d_in[4];
    const float* g1w = (const float*)d_in[5];
    const float* g1b = (const float*)d_in[6];
    const float* g2w = (const float*)d_in[7];
    const float* g2b = (const float*)d_in[8];
    const float* g3w = (const float*)d_in[9];
    const float* g3b = (const float*)d_in[10];
    const float* r1w = (const float*)d_in[11];
    const float* r1b = (const float*)d_in[12];
    const float* r2w = (const float*)d_in[13];
    const float* r2b = (const float*)d_in[14];
    float* out = (float*)d_out;
    float* ws = (float*)d_ws;

    float* h0 = ws;                                   // 16 MB
    float* h1 = ws + 4194304;                         // 32 MB
    float* h2 = ws + 4194304 + 8388608;               // 32 MB
    float* gsum = (float*)((char*)d_ws + 80u * 1024u * 1024u);          // 8 KB
    ushort* wfb = (ushort*)((char*)d_ws + 80u * 1024u * 1024u + 8192u); // 184 KB frag weights

    hipLaunchKernelGGL(zero_kernel, dim3(8), dim3(256), 0, stream, gsum);
    hipLaunchKernelGGL(wprep_kernel, dim3(92), dim3(64), 0, stream,
                       e1w, e2w, g1w, g2w, g3w, wfb);
    hipLaunchKernelGGL(embed_kernel, dim3(1024), dim3(256), 0, stream,
                       obs, wfb, e1b, e2b, h0);
    hipLaunchKernelGGL((gnn_kernel<64, false>), dim3(1024), dim3(256), 0, stream,
                       h0, wfb + 12288, g1b, h1, nullptr);
    hipLaunchKernelGGL((gnn_kernel<128, false>), dim3(1024), dim3(256), 0, stream,
                       h1, wfb + 28672, g2b, h2, nullptr);
    hipLaunchKernelGGL((gnn_kernel<128, true>), dim3(1024), dim3(256), 0, stream,
                       h2, wfb + 61440, g3b, nullptr, gsum);
    hipLaunchKernelGGL(readout_kernel, dim3(16), dim3(256), 0, stream,
                       gsum, r1w, r1b, r2w, r2b, out);
}

// Round 4
// 177.921 us; speedup vs baseline: 1.8851x; 1.2505x over previous
//
#include <hip/hip_runtime.h>

// MFMA bf16x3, R4: streaming branch-free staging + fp32 pad-65 LDS + split-at-consume.
// Intermediates FEATURE-MAJOR h[b][f][n], n = 64x64 grid.
// GNN layer exact rewrite: h' = relu( agg(h) @ W + rowsum*b ).
// fp32 operand split a = hi + lo (bf16 RNE); 3 MFMAs: hi*wh + hi*wl + lo*wh.
//
// MFMA 16x16x32 bf16 layouts (verified m89/m120):
//   A (MxK): m = lane&15, k = quad*8 + j    B (KxN): n = lane&15, k = quad*8 + j
//   C/D: col(N) = lane&15, row(M) = quad*4 + reg
// W in A slot (M=feats), agg-nodes in B slot (N=nodes) -> C cols = nodes.

typedef __attribute__((ext_vector_type(8))) short bf16x8;
typedef __attribute__((ext_vector_type(4))) float f32x4;
#define MFMA(a, b, c) __builtin_amdgcn_mfma_f32_16x16x32_bf16(a, b, c, 0, 0, 0)

__device__ inline ushort bf16h(float x) {
    unsigned u = __float_as_uint(x);
    return (ushort)((u + 0x7fffu + ((u >> 16) & 1u)) >> 16);
}
__device__ inline void split_bf16(float x, ushort& hi, ushort& lo) {
    hi = bf16h(x);
    lo = bf16h(x - __uint_as_float(((unsigned)hi) << 16));
}

__global__ void zero_kernel(float* __restrict__ p) {
    p[blockIdx.x * 256 + threadIdx.x] = 0.f;
}

// ---- weight pre-split into fragment-ordered bf16 hi/lo planes --------------
// Unit (kc,t) = 2 planes x 512 ushorts. Per layer unit index = kc*T + t.
// ushort offsets: e1@0 (4 units), e2@4096 (8), g1@12288 (16), g2@28672 (32), g3@61440 (32).
__global__ __launch_bounds__(64) void wprep_kernel(
    const float* __restrict__ e1w, const float* __restrict__ e2w,
    const float* __restrict__ g1w, const float* __restrict__ g2w,
    const float* __restrict__ g3w, ushort* __restrict__ wf)
{
    const int blk = blockIdx.x, l = threadIdx.x;
    const float* src; int K, N, kc, t; ushort* dst;
    if (blk < 4)        { src = e1w; K = 16;  N = 64;  kc = 0; t = blk;      dst = wf; }
    else if (blk < 12)  { src = e2w; K = 64;  N = 64;  int u = blk - 4;  kc = u >> 2; t = u & 3; dst = wf + 4096; }
    else if (blk < 28)  { src = g1w; K = 64;  N = 128; int u = blk - 12; kc = u >> 3; t = u & 7; dst = wf + 12288; }
    else if (blk < 60)  { src = g2w; K = 128; N = 128; int u = blk - 28; kc = u >> 3; t = u & 7; dst = wf + 28672; }
    else                { src = g3w; K = 128; N = 128; int u = blk - 60; kc = u >> 3; t = u & 7; dst = wf + 61440; }
    const int T = (N == 64) ? 4 : 8;
    ushort* uh = dst + ((kc * T + t) * 2 + 0) * 512 + l * 8;
    ushort* ul = dst + ((kc * T + t) * 2 + 1) * 512 + l * 8;
    const int f = t * 16 + (l & 15);
    const int kb = kc * 32 + ((l >> 4) << 3);
#pragma unroll
    for (int j = 0; j < 8; j++) {
        const int k = kb + j;
        const float w = (k < K) ? src[k * N + f] : 0.f;
        ushort hi, lo; split_bf16(w, hi, lo);
        uh[j] = hi; ul[j] = lo;
    }
}

__device__ inline void frag_from_lds(const float* bp, bf16x8& bh, bf16x8& bl) {
#pragma unroll
    for (int j = 0; j < 8; j++) {
        ushort hi, lo; split_bf16(bp[j * 65], hi, lo);
        bh[j] = (short)hi; bl[j] = (short)lo;
    }
}

// ---- embed: fused 2-layer MLP via MFMA, block = (b, row) = 64 nodes ----
__global__ __launch_bounds__(256, 4) void embed_kernel(
    const float* __restrict__ obs, const ushort* __restrict__ wf,
    const float* __restrict__ e1b, const float* __restrict__ e2b,
    float* __restrict__ h0)
{
    __shared__ float Xs[32 * 65];   // x planes (k>=16 zeroed)
    __shared__ float Hs[64 * 65];   // layer-1 activations
    const int tid = threadIdx.x, b = blockIdx.x >> 6, row = blockIdx.x & 63;
    const int lane = tid & 63, w = tid >> 6, quad = lane >> 4, nl = lane & 15;
    const int cp = tid >> 4, nq = tid & 15;

    // stage x (coalesced float4), zero pad planes
    const float4 x4 = *(const float4*)(obs + ((size_t)(b * 16 + cp) << 12) + row * 64 + nq * 4);
    float* xp = Xs + cp * 65 + nq * 4;
    xp[0] = x4.x; xp[1] = x4.y; xp[2] = x4.z; xp[3] = x4.w;
    float* zp = Xs + (16 + cp) * 65 + nq * 4;
    zp[0] = 0.f; zp[1] = 0.f; zp[2] = 0.f; zp[3] = 0.f;
    __syncthreads();

    // layer 1: wave w -> mid-feats 16w..16w+15
    {
        const ushort* wp = wf + lane * 8;
        const bf16x8 wh = *(const bf16x8*)(wp + (w * 2) * 512);
        const bf16x8 wl = *(const bf16x8*)(wp + (w * 2 + 1) * 512);
#pragma unroll
        for (int nt = 0; nt < 4; nt++) {
            const float* bp = Xs + (quad * 8) * 65 + nt * 16 + nl;
            bf16x8 bh, bl; frag_from_lds(bp, bh, bl);
            f32x4 c = {0.f, 0.f, 0.f, 0.f};
            c = MFMA(wh, bh, c); c = MFMA(wh, bl, c); c = MFMA(wl, bh, c);
#pragma unroll
            for (int reg = 0; reg < 4; reg++) {
                const int fm = 16 * w + quad * 4 + reg;
                Hs[fm * 65 + nt * 16 + nl] = fmaxf(c[reg] + e1b[fm], 0.f);
            }
        }
    }
    __syncthreads();

    // layer 2: K=64 (2 kc)
    const ushort* e2f = wf + 4096;
    f32x4 a2[4];
#pragma unroll
    for (int nt = 0; nt < 4; nt++) a2[nt] = (f32x4){0.f, 0.f, 0.f, 0.f};
#pragma unroll
    for (int kc = 0; kc < 2; kc++) {
        const ushort* wp = e2f + lane * 8;
        const bf16x8 wh = *(const bf16x8*)(wp + ((kc * 4 + w) * 2) * 512);
        const bf16x8 wl = *(const bf16x8*)(wp + ((kc * 4 + w) * 2 + 1) * 512);
#pragma unroll
        for (int nt = 0; nt < 4; nt++) {
            const float* bp = Hs + (kc * 32 + quad * 8) * 65 + nt * 16 + nl;
            bf16x8 bh, bl; frag_from_lds(bp, bh, bl);
            a2[nt] = MFMA(wh, bh, a2[nt]);
            a2[nt] = MFMA(wh, bl, a2[nt]);
            a2[nt] = MFMA(wl, bh, a2[nt]);
        }
    }
#pragma unroll
    for (int reg = 0; reg < 4; reg++) {
        const int f = 16 * w + quad * 4 + reg;
        const float bv = e2b[f];
#pragma unroll
        for (int nt = 0; nt < 4; nt++)
            h0[((size_t)(b * 64 + f) << 12) + row * 64 + nt * 16 + nl] =
                fmaxf(a2[nt][reg] + bv, 0.f);
    }
}

// ---- GNN layer: block = (b, row); streaming agg staging + split-at-consume ----
template <int K, bool MEAN>
__global__ __launch_bounds__(256, 4) void gnn_kernel(
    const float* __restrict__ hin, const ushort* __restrict__ wf,
    const float* __restrict__ bias, float* __restrict__ hout,
    float* __restrict__ gsum)
{
    constexpr int NH = K / 64;            // 64-plane halves
    __shared__ float As[64 * 65];
    const int tid = threadIdx.x, b = blockIdx.x >> 6, row = blockIdx.x & 63;
    const int lane = tid & 63, w = tid >> 6, quad = lane >> 4, nl = lane & 15;
    const int kp = tid >> 4, nq = tid & 15;
    const float* hb = hin + (size_t)b * K * 4096;
    const int rowu = (row > 0) ? row - 1 : row;
    const int rowd = (row < 63) ? row + 1 : row;
    const float su = (row > 0) ? 1.f : 0.f;
    const float sd = (row < 63) ? 1.f : 0.f;
    float inv[4];
#pragma unroll
    for (int i = 0; i < 4; i++) {
        const int n = nq * 4 + i;
        const int deg = (row > 0) + (row < 63) + (n > 0) + (n < 63);
        inv[i] = 1.f / ((float)deg + 1e-6f);
    }

    f32x4 acc[4][2];
#pragma unroll
    for (int nt = 0; nt < 4; nt++) {
        acc[nt][0] = (f32x4){0.f, 0.f, 0.f, 0.f};
        acc[nt][1] = (f32x4){0.f, 0.f, 0.f, 0.f};
    }

    for (int kh = 0; kh < NH; kh++) {
        // ---- stage 64 aggregated planes: branch-free float4 loads ----
#pragma unroll
        for (int it = 0; it < 4; it++) {
            const int kk = it * 16 + kp;
            const float* pk = hb + ((size_t)(kh * 64 + kk) << 12) + nq * 4;
            const float4 c4 = *(const float4*)(pk + row * 64);
            const float4 u4 = *(const float4*)(pk + rowu * 64);
            const float4 d4 = *(const float4*)(pk + rowd * 64);
            const float pw = __shfl_up(c4.w, 1);
            const float nx = __shfl_down(c4.x, 1);
            const float lx = (nq > 0) ? pw : 0.f;
            const float rw = (nq < 15) ? nx : 0.f;
            float* ap = As + kk * 65 + nq * 4;
            ap[0] = (su * u4.x + sd * d4.x + lx + c4.y) * inv[0];
            ap[1] = (su * u4.y + sd * d4.y + c4.x + c4.z) * inv[1];
            ap[2] = (su * u4.z + sd * d4.z + c4.y + c4.w) * inv[2];
            ap[3] = (su * u4.w + sd * d4.w + c4.z + rw) * inv[3];
        }
        __syncthreads();
        // ---- consume: frags split in-register, 6 MFMA per (nt,kc) ----
#pragma unroll
        for (int kc = 0; kc < 2; kc++) {
            const int kcg = kh * 2 + kc;
            const ushort* wp = wf + lane * 8;
            const bf16x8 wh0 = *(const bf16x8*)(wp + ((kcg * 8 + 2 * w)     * 2)     * 512);
            const bf16x8 wl0 = *(const bf16x8*)(wp + ((kcg * 8 + 2 * w)     * 2 + 1) * 512);
            const bf16x8 wh1 = *(const bf16x8*)(wp + ((kcg * 8 + 2 * w + 1) * 2)     * 512);
            const bf16x8 wl1 = *(const bf16x8*)(wp + ((kcg * 8 + 2 * w + 1) * 2 + 1) * 512);
#pragma unroll
            for (int nt = 0; nt < 4; nt++) {
                const float* bp = As + (kc * 32 + quad * 8) * 65 + nt * 16 + nl;
                bf16x8 bh, bl; frag_from_lds(bp, bh, bl);
                acc[nt][0] = MFMA(wh0, bh, acc[nt][0]);
                acc[nt][0] = MFMA(wh0, bl, acc[nt][0]);
                acc[nt][0] = MFMA(wl0, bh, acc[nt][0]);
                acc[nt][1] = MFMA(wh1, bh, acc[nt][1]);
                acc[nt][1] = MFMA(wh1, bl, acc[nt][1]);
                acc[nt][1] = MFMA(wl1, bh, acc[nt][1]);
            }
        }
        __syncthreads();
    }

    // ---- epilogue: + rowsum*bias, relu ----
    if (!MEAN) {
#pragma unroll
        for (int ftl = 0; ftl < 2; ftl++) {
            const int fb = 32 * w + 16 * ftl + quad * 4;
            const float b0 = bias[fb], b1 = bias[fb + 1], b2 = bias[fb + 2], b3 = bias[fb + 3];
#pragma unroll
            for (int nt = 0; nt < 4; nt++) {
                const int n = 16 * nt + nl;
                const int deg = (row > 0) + (row < 63) + (n > 0) + (n < 63);
                const float rs = (float)deg / ((float)deg + 1e-6f);
                float* op = hout + ((size_t)(b * 128 + fb) << 12) + row * 64 + n;
                op[0]        = fmaxf(acc[nt][ftl][0] + rs * b0, 0.f);
                op[1u << 12] = fmaxf(acc[nt][ftl][1] + rs * b1, 0.f);
                op[2u << 12] = fmaxf(acc[nt][ftl][2] + rs * b2, 0.f);
                op[3u << 12] = fmaxf(acc[nt][ftl][3] + rs * b3, 0.f);
            }
        }
    } else {
#pragma unroll
        for (int ftl = 0; ftl < 2; ftl++) {
            const int fb = 32 * w + 16 * ftl + quad * 4;
#pragma unroll
            for (int reg = 0; reg < 4; reg++) {
                const float bv = bias[fb + reg];
                float v = 0.f;
#pragma unroll
                for (int nt = 0; nt < 4; nt++) {
                    const int n = 16 * nt + nl;
                    const int deg = (row > 0) + (row < 63) + (n > 0) + (n < 63);
                    const float rs = (float)deg / ((float)deg + 1e-6f);
                    v += fmaxf(acc[nt][ftl][reg] + rs * bv, 0.f);
                }
                v += __shfl_xor(v, 1); v += __shfl_xor(v, 2);
                v += __shfl_xor(v, 4); v += __shfl_xor(v, 8);
                if (nl == 0) atomicAdd(&gsum[b * 128 + fb + reg], v * (1.f / 4096.f));
            }
        }
    }
}

// ---- readout: per-batch block, 2-layer MLP (fp32 vector) ----
__global__ __launch_bounds__(256) void readout_kernel(
    const float* __restrict__ gsum, const float* __restrict__ r1w,
    const float* __restrict__ r1b, const float* __restrict__ r2w,
    const float* __restrict__ r2b, float* __restrict__ out)
{
    __shared__ float gs[128];
    __shared__ float g2[256];
    const int b = blockIdx.x, tid = threadIdx.x;
    if (tid < 128) gs[tid] = gsum[b * 128 + tid];
    __syncthreads();
    float a = r1b[tid];
#pragma unroll 16
    for (int k = 0; k < 128; k++) a = fmaf(gs[k], r1w[k * 256 + tid], a);
    g2[tid] = fmaxf(a, 0.f);
    __syncthreads();
    float a2 = r2b[tid];
#pragma unroll 16
    for (int k = 0; k < 256; k++) a2 = fmaf(g2[k], r2w[k * 256 + tid], a2);
    out[b * 256 + tid] = fmaxf(a2, 0.f);
}

extern "C" void kernel_launch(void* const* d_in, const int* in_sizes, int n_in,
                              void* d_out, int out_size, void* d_ws, size_t ws_size,
                              hipStream_t stream)
{
    const float* obs = (const float*)d_in[0];
    const float* e1w = (const float*)d_in[1];
    const float* e1b = (const float*)d_in[2];
    const float* e2w = (const float*)d_in[3];
    const float* e2b = (const float*)d_in[4];
    const float* g1w = (const float*)d_in[5];
    const float* g1b = (const float*)d_in[6];
    const float* g2w = (const float*)d_in[7];
    const float* g2b = (const float*)d_in[8];
    const float* g3w = (const float*)d_in[9];
    const float* g3b = (const float*)d_in[10];
    const float* r1w = (const float*)d_in[11];
    const float* r1b = (const float*)d_in[12];
    const float* r2w = (const float*)d_in[13];
    const float* r2b = (const float*)d_in[14];
    float* out = (float*)d_out;
    float* ws = (float*)d_ws;

    float* h0 = ws;                                   // 16 MB
    float* h1 = ws + 4194304;                         // 32 MB
    float* h2 = ws + 4194304 + 8388608;               // 32 MB
    float* gsum = (float*)((char*)d_ws + 80u * 1024u * 1024u);          // 8 KB
    ushort* wfb = (ushort*)((char*)d_ws + 80u * 1024u * 1024u + 8192u); // 184 KB

    hipLaunchKernelGGL(zero_kernel, dim3(8), dim3(256), 0, stream, gsum);
    hipLaunchKernelGGL(wprep_kernel, dim3(92), dim3(64), 0, stream,
                       e1w, e2w, g1w, g2w, g3w, wfb);
    hipLaunchKernelGGL(embed_kernel, dim3(1024), dim3(256), 0, stream,
                       obs, wfb, e1b, e2b, h0);
    hipLaunchKernelGGL((gnn_kernel<64, false>), dim3(1024), dim3(256), 0, stream,
                       h0, wfb + 12288, g1b, h1, nullptr);
    hipLaunchKernelGGL((gnn_kernel<128, false>), dim3(1024), dim3(256), 0, stream,
                       h1, wfb + 28672, g2b, h2, nullptr);
    hipLaunchKernelGGL((gnn_kernel<128, true>), dim3(1024), dim3(256), 0, stream,
                       h2, wfb + 61440, g3b, nullptr, gsum);
    hipLaunchKernelGGL(readout_kernel, dim3(16), dim3(256), 0, stream,
                       gsum, r1w, r1b, r2w, r2b, out);
}

// Round 5
// 165.784 us; speedup vs baseline: 2.0231x; 1.0732x over previous
//
#include <hip/hip_runtime.h>

// MFMA bf16x3, R5: deep-batched register staging, double-buffered LDS halves,
// packed hi|lo split-at-stage (u32, pad-65, conflict-free), XCD-contig remap.
// Intermediates FEATURE-MAJOR h[b][f][n], n = 64x64 grid.
// GNN layer exact rewrite: h' = relu( agg(h) @ W + rowsum*b ).
// fp32 split a = hi + lo (bf16 RNE); 3 MFMAs: hi*wh + hi*wl + lo*wh.
//
// MFMA 16x16x32 bf16 layouts (verified m89/m120):
//   A (MxK): m = lane&15, k = quad*8 + j    B (KxN): n = lane&15, k = quad*8 + j
//   C/D: col(N) = lane&15, row(M) = quad*4 + reg
// W in A slot (M=feats), agg-nodes in B slot (N=nodes) -> C cols = nodes.

typedef __attribute__((ext_vector_type(8))) short bf16x8;
typedef __attribute__((ext_vector_type(4))) float f32x4;
#define MFMA(a, b, c) __builtin_amdgcn_mfma_f32_16x16x32_bf16(a, b, c, 0, 0, 0)

__device__ inline ushort bf16h(float x) {
    unsigned u = __float_as_uint(x);
    return (ushort)((u + 0x7fffu + ((u >> 16) & 1u)) >> 16);
}
__device__ inline void split_bf16(float x, ushort& hi, ushort& lo) {
    hi = bf16h(x);
    lo = bf16h(x - __uint_as_float(((unsigned)hi) << 16));
}
// packed (hi16 << 16) | lo16
__device__ inline unsigned pack_split(float x) {
    unsigned u = __float_as_uint(x);
    unsigned hi = (u + 0x7fffu + ((u >> 16) & 1u)) >> 16;
    float r = x - __uint_as_float(hi << 16);
    unsigned v = __float_as_uint(r);
    unsigned lo = (v + 0x7fffu + ((v >> 16) & 1u)) >> 16;
    return (hi << 16) | lo;
}
// 8 packed u32 (stride 65) -> hi/lo bf16x8 fragments
__device__ inline void frag_packed(const unsigned* bp, bf16x8& bh, bf16x8& bl) {
    unsigned p[8];
#pragma unroll
    for (int j = 0; j < 8; j++) p[j] = bp[j * 65];
    union { bf16x8 v; unsigned d[4]; } H, L;
#pragma unroll
    for (int j = 0; j < 4; j++) {
        const unsigned e = p[2 * j], o = p[2 * j + 1];
        H.d[j] = (o & 0xFFFF0000u) | (e >> 16);
        L.d[j] = (o << 16) | (e & 0xFFFFu);
    }
    bh = H.v; bl = L.v;
}

__global__ void zero_kernel(float* __restrict__ p) {
    p[blockIdx.x * 256 + threadIdx.x] = 0.f;
}

// ---- weight pre-split into fragment-ordered bf16 hi/lo planes --------------
// Unit (kc,t) = 2 planes x 512 ushorts. Per layer unit index = kc*T + t.
// ushort offsets: e1@0 (4 units), e2@4096 (8), g1@12288 (16), g2@28672 (32), g3@61440 (32).
__global__ __launch_bounds__(64) void wprep_kernel(
    const float* __restrict__ e1w, const float* __restrict__ e2w,
    const float* __restrict__ g1w, const float* __restrict__ g2w,
    const float* __restrict__ g3w, ushort* __restrict__ wf)
{
    const int blk = blockIdx.x, l = threadIdx.x;
    const float* src; int K, N, kc, t; ushort* dst;
    if (blk < 4)        { src = e1w; K = 16;  N = 64;  kc = 0; t = blk;      dst = wf; }
    else if (blk < 12)  { src = e2w; K = 64;  N = 64;  int u = blk - 4;  kc = u >> 2; t = u & 3; dst = wf + 4096; }
    else if (blk < 28)  { src = g1w; K = 64;  N = 128; int u = blk - 12; kc = u >> 3; t = u & 7; dst = wf + 12288; }
    else if (blk < 60)  { src = g2w; K = 128; N = 128; int u = blk - 28; kc = u >> 3; t = u & 7; dst = wf + 28672; }
    else                { src = g3w; K = 128; N = 128; int u = blk - 60; kc = u >> 3; t = u & 7; dst = wf + 61440; }
    const int T = (N == 64) ? 4 : 8;
    ushort* uh = dst + ((kc * T + t) * 2 + 0) * 512 + l * 8;
    ushort* ul = dst + ((kc * T + t) * 2 + 1) * 512 + l * 8;
    const int f = t * 16 + (l & 15);
    const int kb = kc * 32 + ((l >> 4) << 3);
#pragma unroll
    for (int j = 0; j < 8; j++) {
        const int k = kb + j;
        const float w = (k < K) ? src[k * N + f] : 0.f;
        ushort hi, lo; split_bf16(w, hi, lo);
        uh[j] = hi; ul[j] = lo;
    }
}

// ---- embed: fused 2-layer MLP via MFMA, block = (b, row) = 64 nodes ----
__global__ __launch_bounds__(256, 4) void embed_kernel(
    const float* __restrict__ obs, const ushort* __restrict__ wf,
    const float* __restrict__ e1b, const float* __restrict__ e2b,
    float* __restrict__ h0)
{
    __shared__ unsigned Xs[32 * 65];   // packed x planes (k>=16 zeroed)
    __shared__ unsigned Hs[64 * 65];   // packed layer-1 activations
    const int tid = threadIdx.x, b = blockIdx.x >> 6, row = blockIdx.x & 63;
    const int lane = tid & 63, w = tid >> 6, quad = lane >> 4, nl = lane & 15;
    const int cp = tid >> 4, nq = tid & 15;

    // stage x (coalesced float4), packed split; zero pad planes
    const float4 x4 = *(const float4*)(obs + ((size_t)(b * 16 + cp) << 12) + row * 64 + nq * 4);
    unsigned* xp = Xs + cp * 65 + nq * 4;
    xp[0] = pack_split(x4.x); xp[1] = pack_split(x4.y);
    xp[2] = pack_split(x4.z); xp[3] = pack_split(x4.w);
    unsigned* zp = Xs + (16 + cp) * 65 + nq * 4;
    zp[0] = 0u; zp[1] = 0u; zp[2] = 0u; zp[3] = 0u;
    __syncthreads();

    // layer 1: wave w -> mid-feats 16w..16w+15
    {
        const ushort* wp = wf + lane * 8;
        const bf16x8 wh = *(const bf16x8*)(wp + (w * 2) * 512);
        const bf16x8 wl = *(const bf16x8*)(wp + (w * 2 + 1) * 512);
#pragma unroll
        for (int nt = 0; nt < 4; nt++) {
            const unsigned* bp = Xs + (quad * 8) * 65 + nt * 16 + nl;
            bf16x8 bh, bl; frag_packed(bp, bh, bl);
            f32x4 c = {0.f, 0.f, 0.f, 0.f};
            c = MFMA(wh, bh, c); c = MFMA(wh, bl, c); c = MFMA(wl, bh, c);
#pragma unroll
            for (int reg = 0; reg < 4; reg++) {
                const int fm = 16 * w + quad * 4 + reg;
                Hs[fm * 65 + nt * 16 + nl] = pack_split(fmaxf(c[reg] + e1b[fm], 0.f));
            }
        }
    }
    __syncthreads();

    // layer 2: K=64 (2 kc)
    const ushort* e2f = wf + 4096;
    f32x4 a2[4];
#pragma unroll
    for (int nt = 0; nt < 4; nt++) a2[nt] = (f32x4){0.f, 0.f, 0.f, 0.f};
#pragma unroll
    for (int kc = 0; kc < 2; kc++) {
        const ushort* wp = e2f + lane * 8;
        const bf16x8 wh = *(const bf16x8*)(wp + ((kc * 4 + w) * 2) * 512);
        const bf16x8 wl = *(const bf16x8*)(wp + ((kc * 4 + w) * 2 + 1) * 512);
#pragma unroll
        for (int nt = 0; nt < 4; nt++) {
            const unsigned* bp = Hs + (kc * 32 + quad * 8) * 65 + nt * 16 + nl;
            bf16x8 bh, bl; frag_packed(bp, bh, bl);
            a2[nt] = MFMA(wh, bh, a2[nt]);
            a2[nt] = MFMA(wh, bl, a2[nt]);
            a2[nt] = MFMA(wl, bh, a2[nt]);
        }
    }
#pragma unroll
    for (int reg = 0; reg < 4; reg++) {
        const int f = 16 * w + quad * 4 + reg;
        const float bv = e2b[f];
#pragma unroll
        for (int nt = 0; nt < 4; nt++)
            h0[((size_t)(b * 64 + f) << 12) + row * 64 + nt * 16 + nl] =
                fmaxf(a2[nt][reg] + bv, 0.f);
    }
}

// ---- GNN layer: block = (b, row); batched reg loads, dbuf halves, packed LDS ----
template <int K, bool MEAN>
__global__ __launch_bounds__(256, 4) void gnn_kernel(
    const float* __restrict__ hin, const ushort* __restrict__ wf,
    const float* __restrict__ bias, float* __restrict__ hout,
    float* __restrict__ gsum)
{
    constexpr int NH = K / 64;            // 64-plane halves
    __shared__ unsigned As[NH][64 * 65];  // packed hi|lo
    const int tid = threadIdx.x;
    // XCD-contiguous remap: each XCD (blk%8) owns 128 consecutive (b,row) ids
    const int bid = ((blockIdx.x & 7) << 7) | (blockIdx.x >> 3);
    const int b = bid >> 6, row = bid & 63;
    const int lane = tid & 63, w = tid >> 6, quad = lane >> 4, nl = lane & 15;
    const int kp = tid >> 4, nq = tid & 15;
    const float* hb = hin + (size_t)b * K * 4096;
    const int rowu = (row > 0) ? row - 1 : row;
    const int rowd = (row < 63) ? row + 1 : row;
    const float su = (row > 0) ? 1.f : 0.f;
    const float sd = (row < 63) ? 1.f : 0.f;
    float inv[4];
#pragma unroll
    for (int i = 0; i < 4; i++) {
        const int n = nq * 4 + i;
        const int deg = (row > 0) + (row < 63) + (n > 0) + (n < 63);
        inv[i] = 1.f / ((float)deg + 1e-6f);
    }

    f32x4 acc[4][2];
#pragma unroll
    for (int nt = 0; nt < 4; nt++) {
        acc[nt][0] = (f32x4){0.f, 0.f, 0.f, 0.f};
        acc[nt][1] = (f32x4){0.f, 0.f, 0.f, 0.f};
    }

    float4 c4[4], u4[4], d4[4];           // deep load batch (12 dwordx4 in flight)
    auto load_half = [&](int kh) {
#pragma unroll
        for (int it = 0; it < 4; it++) {
            const int kk = it * 16 + kp;
            const float* pk = hb + ((size_t)(kh * 64 + kk) << 12) + nq * 4;
            c4[it] = *(const float4*)(pk + row * 64);
            u4[it] = *(const float4*)(pk + rowu * 64);
            d4[it] = *(const float4*)(pk + rowd * 64);
        }
    };
    auto stage = [&](int kh) {
        unsigned* dst = As[kh];
#pragma unroll
        for (int it = 0; it < 4; it++) {
            const int kk = it * 16 + kp;
            const float pw = __shfl_up(c4[it].w, 1);
            const float nx = __shfl_down(c4[it].x, 1);
            const float lx = (nq > 0) ? pw : 0.f;
            const float rw = (nq < 15) ? nx : 0.f;
            unsigned* ap = dst + kk * 65 + nq * 4;
            ap[0] = pack_split((su * u4[it].x + sd * d4[it].x + lx + c4[it].y) * inv[0]);
            ap[1] = pack_split((su * u4[it].y + sd * d4[it].y + c4[it].x + c4[it].z) * inv[1]);
            ap[2] = pack_split((su * u4[it].z + sd * d4[it].z + c4[it].y + c4[it].w) * inv[2]);
            ap[3] = pack_split((su * u4[it].w + sd * d4[it].w + c4[it].z + rw) * inv[3]);
        }
    };
    auto consume = [&](int kh) {
        const unsigned* src = As[kh];
#pragma unroll
        for (int kc = 0; kc < 2; kc++) {
            const int kcg = kh * 2 + kc;
            const ushort* wp = wf + lane * 8;
            const bf16x8 wh0 = *(const bf16x8*)(wp + ((kcg * 8 + 2 * w)     * 2)     * 512);
            const bf16x8 wl0 = *(const bf16x8*)(wp + ((kcg * 8 + 2 * w)     * 2 + 1) * 512);
            const bf16x8 wh1 = *(const bf16x8*)(wp + ((kcg * 8 + 2 * w + 1) * 2)     * 512);
            const bf16x8 wl1 = *(const bf16x8*)(wp + ((kcg * 8 + 2 * w + 1) * 2 + 1) * 512);
#pragma unroll
            for (int nt = 0; nt < 4; nt++) {
                const unsigned* bp = src + (kc * 32 + quad * 8) * 65 + nt * 16 + nl;
                bf16x8 bh, bl; frag_packed(bp, bh, bl);
                acc[nt][0] = MFMA(wh0, bh, acc[nt][0]);
                acc[nt][0] = MFMA(wh0, bl, acc[nt][0]);
                acc[nt][0] = MFMA(wl0, bh, acc[nt][0]);
                acc[nt][1] = MFMA(wh1, bh, acc[nt][1]);
                acc[nt][1] = MFMA(wh1, bl, acc[nt][1]);
                acc[nt][1] = MFMA(wl1, bh, acc[nt][1]);
            }
        }
    };

    // software pipeline: loads of half kh+1 overlap consume of half kh
    load_half(0);
    stage(0);
    __syncthreads();
#pragma unroll
    for (int kh = 0; kh < NH; kh++) {
        if (kh + 1 < NH) load_half(kh + 1);
        consume(kh);
        if (kh + 1 < NH) {
            stage(kh + 1);       // writes buf kh+1; others may still read buf kh: OK
            __syncthreads();
        }
    }

    // ---- epilogue: + rowsum*bias, relu ----
    if (!MEAN) {
#pragma unroll
        for (int ftl = 0; ftl < 2; ftl++) {
            const int fb = 32 * w + 16 * ftl + quad * 4;
            const float b0 = bias[fb], b1 = bias[fb + 1], b2 = bias[fb + 2], b3 = bias[fb + 3];
#pragma unroll
            for (int nt = 0; nt < 4; nt++) {
                const int n = 16 * nt + nl;
                const int deg = (row > 0) + (row < 63) + (n > 0) + (n < 63);
                const float rs = (float)deg / ((float)deg + 1e-6f);
                float* op = hout + ((size_t)(b * 128 + fb) << 12) + row * 64 + n;
                op[0]        = fmaxf(acc[nt][ftl][0] + rs * b0, 0.f);
                op[1u << 12] = fmaxf(acc[nt][ftl][1] + rs * b1, 0.f);
                op[2u << 12] = fmaxf(acc[nt][ftl][2] + rs * b2, 0.f);
                op[3u << 12] = fmaxf(acc[nt][ftl][3] + rs * b3, 0.f);
            }
        }
    } else {
#pragma unroll
        for (int ftl = 0; ftl < 2; ftl++) {
            const int fb = 32 * w + 16 * ftl + quad * 4;
#pragma unroll
            for (int reg = 0; reg < 4; reg++) {
                const float bv = bias[fb + reg];
                float v = 0.f;
#pragma unroll
                for (int nt = 0; nt < 4; nt++) {
                    const int n = 16 * nt + nl;
                    const int deg = (row > 0) + (row < 63) + (n > 0) + (n < 63);
                    const float rs = (float)deg / ((float)deg + 1e-6f);
                    v += fmaxf(acc[nt][ftl][reg] + rs * bv, 0.f);
                }
                v += __shfl_xor(v, 1); v += __shfl_xor(v, 2);
                v += __shfl_xor(v, 4); v += __shfl_xor(v, 8);
                if (nl == 0) atomicAdd(&gsum[b * 128 + fb + reg], v * (1.f / 4096.f));
            }
        }
    }
}

// ---- readout: per-batch block, 2-layer MLP (fp32 vector) ----
__global__ __launch_bounds__(256) void readout_kernel(
    const float* __restrict__ gsum, const float* __restrict__ r1w,
    const float* __restrict__ r1b, const float* __restrict__ r2w,
    const float* __restrict__ r2b, float* __restrict__ out)
{
    __shared__ float gs[128];
    __shared__ float g2[256];
    const int b = blockIdx.x, tid = threadIdx.x;
    if (tid < 128) gs[tid] = gsum[b * 128 + tid];
    __syncthreads();
    float a = r1b[tid];
#pragma unroll 16
    for (int k = 0; k < 128; k++) a = fmaf(gs[k], r1w[k * 256 + tid], a);
    g2[tid] = fmaxf(a, 0.f);
    __syncthreads();
    float a2 = r2b[tid];
#pragma unroll 16
    for (int k = 0; k < 256; k++) a2 = fmaf(g2[k], r2w[k * 256 + tid], a2);
    out[b * 256 + tid] = fmaxf(a2, 0.f);
}

extern "C" void kernel_launch(void* const* d_in, const int* in_sizes, int n_in,
                              void* d_out, int out_size, void* d_ws, size_t ws_size,
                              hipStream_t stream)
{
    const float* obs = (const float*)d_in[0];
    const float* e1w = (const float*)d_in[1];
    const float* e1b = (const float*)d_in[2];
    const float* e2w = (const float*)d_in[3];
    const float* e2b = (const float*)d_in[4];
    const float* g1w = (const float*)d_in[5];
    const float* g1b = (const float*)d_in[6];
    const float* g2w = (const float*)d_in[7];
    const float* g2b = (const float*)d_in[8];
    const float* g3w = (const float*)d_in[9];
    const float* g3b = (const float*)d_in[10];
    const float* r1w = (const float*)d_in[11];
    const float* r1b = (const float*)d_in[12];
    const float* r2w = (const float*)d_in[13];
    const float* r2b = (const float*)d_in[14];
    float* out = (float*)d_out;
    float* ws = (float*)d_ws;

    float* h0 = ws;                                   // 16 MB
    float* h1 = ws + 4194304;                         // 32 MB
    float* h2 = ws + 4194304 + 8388608;               // 32 MB
    float* gsum = (float*)((char*)d_ws + 80u * 1024u * 1024u);          // 8 KB
    ushort* wfb = (ushort*)((char*)d_ws + 80u * 1024u * 1024u + 8192u); // 184 KB

    hipLaunchKernelGGL(zero_kernel, dim3(8), dim3(256), 0, stream, gsum);
    hipLaunchKernelGGL(wprep_kernel, dim3(92), dim3(64), 0, stream,
                       e1w, e2w, g1w, g2w, g3w, wfb);
    hipLaunchKernelGGL(embed_kernel, dim3(1024), dim3(256), 0, stream,
                       obs, wfb, e1b, e2b, h0);
    hipLaunchKernelGGL((gnn_kernel<64, false>), dim3(1024), dim3(256), 0, stream,
                       h0, wfb + 12288, g1b, h1, nullptr);
    hipLaunchKernelGGL((gnn_kernel<128, false>), dim3(1024), dim3(256), 0, stream,
                       h1, wfb + 28672, g2b, h2, nullptr);
    hipLaunchKernelGGL((gnn_kernel<128, true>), dim3(1024), dim3(256), 0, stream,
                       h2, wfb + 61440, g3b, nullptr, gsum);
    hipLaunchKernelGGL(readout_kernel, dim3(16), dim3(256), 0, stream,
                       gsum, r1w, r1b, r2w, r2b, out);
}

// Round 6
// 163.125 us; speedup vs baseline: 2.0561x; 1.0163x over previous
//
#include <hip/hip_runtime.h>

// MFMA bf16x3, R6: register-budget fix. Rolling 2-group staging pipeline
// (<=6 float4 live, ~110 VGPR peak -> no spills under (256,4)), packed hi|lo
// split-at-stage (u32, pad-65, conflict-free LDS), dbuf halves, XCD remap.
// Intermediates FEATURE-MAJOR h[b][f][n], n = 64x64 grid.
// GNN layer exact rewrite: h' = relu( agg(h) @ W + rowsum*b ).
// fp32 split a = hi + lo (bf16); 3 MFMAs: hi*wh + hi*wl + lo*wh.
//
// MFMA 16x16x32 bf16 layouts (verified m89/m120):
//   A (MxK): m = lane&15, k = quad*8 + j    B (KxN): n = lane&15, k = quad*8 + j
//   C/D: col(N) = lane&15, row(M) = quad*4 + reg
// W in A slot (M=feats), agg-nodes in B slot (N=nodes) -> C cols = nodes.

typedef __attribute__((ext_vector_type(8))) short bf16x8;
typedef __attribute__((ext_vector_type(4))) float f32x4;
#define MFMA(a, b, c) __builtin_amdgcn_mfma_f32_16x16x32_bf16(a, b, c, 0, 0, 0)

__device__ inline ushort bf16h(float x) {
    unsigned u = __float_as_uint(x);
    return (ushort)((u + 0x7fffu + ((u >> 16) & 1u)) >> 16);
}
__device__ inline void split_bf16(float x, ushort& hi, ushort& lo) {
    hi = bf16h(x);
    lo = bf16h(x - __uint_as_float(((unsigned)hi) << 16));
}
// packed (hi16 << 16) | lo16 ; hi = RNE, lo = truncation (err ~2^-17 rel, OK)
__device__ inline unsigned pack_split(float x) {
    unsigned u = __float_as_uint(x);
    unsigned hi = (u + 0x7fffu + ((u >> 16) & 1u)) >> 16;
    float r = x - __uint_as_float(hi << 16);
    return (hi << 16) | (__float_as_uint(r) >> 16);
}
// 8 packed u32 (stride 65) -> hi/lo bf16x8 fragments
__device__ inline void frag_packed(const unsigned* bp, bf16x8& bh, bf16x8& bl) {
    unsigned p[8];
#pragma unroll
    for (int j = 0; j < 8; j++) p[j] = bp[j * 65];
    union { bf16x8 v; unsigned d[4]; } H, L;
#pragma unroll
    for (int j = 0; j < 4; j++) {
        const unsigned e = p[2 * j], o = p[2 * j + 1];
        H.d[j] = (o & 0xFFFF0000u) | (e >> 16);
        L.d[j] = (o << 16) | (e & 0xFFFFu);
    }
    bh = H.v; bl = L.v;
}

// ---- weight pre-split into fragment-ordered bf16 hi/lo planes (+ gsum zero) --
// Unit (kc,t) = 2 planes x 512 ushorts. Per layer unit index = kc*T + t.
// ushort offsets: e1@0 (4 units), e2@4096 (8), g1@12288 (16), g2@28672 (32), g3@61440 (32).
__global__ __launch_bounds__(64) void wprep_kernel(
    const float* __restrict__ e1w, const float* __restrict__ e2w,
    const float* __restrict__ g1w, const float* __restrict__ g2w,
    const float* __restrict__ g3w, ushort* __restrict__ wf,
    float* __restrict__ gsum)
{
    const int blk = blockIdx.x, l = threadIdx.x;
    if (blk >= 92) {                       // 32 blocks x 64 = 2048: zero gsum
        gsum[(blk - 92) * 64 + l] = 0.f;
        return;
    }
    const float* src; int K, N, kc, t; ushort* dst;
    if (blk < 4)        { src = e1w; K = 16;  N = 64;  kc = 0; t = blk;      dst = wf; }
    else if (blk < 12)  { src = e2w; K = 64;  N = 64;  int u = blk - 4;  kc = u >> 2; t = u & 3; dst = wf + 4096; }
    else if (blk < 28)  { src = g1w; K = 64;  N = 128; int u = blk - 12; kc = u >> 3; t = u & 7; dst = wf + 12288; }
    else if (blk < 60)  { src = g2w; K = 128; N = 128; int u = blk - 28; kc = u >> 3; t = u & 7; dst = wf + 28672; }
    else                { src = g3w; K = 128; N = 128; int u = blk - 60; kc = u >> 3; t = u & 7; dst = wf + 61440; }
    const int T = (N == 64) ? 4 : 8;
    ushort* uh = dst + ((kc * T + t) * 2 + 0) * 512 + l * 8;
    ushort* ul = dst + ((kc * T + t) * 2 + 1) * 512 + l * 8;
    const int f = t * 16 + (l & 15);
    const int kb = kc * 32 + ((l >> 4) << 3);
#pragma unroll
    for (int j = 0; j < 8; j++) {
        const int k = kb + j;
        const float w = (k < K) ? src[k * N + f] : 0.f;
        ushort hi, lo; split_bf16(w, hi, lo);
        uh[j] = hi; ul[j] = lo;
    }
}

// ---- embed: fused 2-layer MLP via MFMA, block = (b, row) = 64 nodes ----
__global__ __launch_bounds__(256, 4) void embed_kernel(
    const float* __restrict__ obs, const ushort* __restrict__ wf,
    const float* __restrict__ e1b, const float* __restrict__ e2b,
    float* __restrict__ h0)
{
    __shared__ unsigned Xs[32 * 65];   // packed x planes (k>=16 zeroed)
    __shared__ unsigned Hs[64 * 65];   // packed layer-1 activations
    const int tid = threadIdx.x, b = blockIdx.x >> 6, row = blockIdx.x & 63;
    const int lane = tid & 63, w = tid >> 6, quad = lane >> 4, nl = lane & 15;
    const int cp = tid >> 4, nq = tid & 15;

    // stage x (coalesced float4), packed split; zero pad planes
    const float4 x4 = *(const float4*)(obs + ((size_t)(b * 16 + cp) << 12) + row * 64 + nq * 4);
    unsigned* xp = Xs + cp * 65 + nq * 4;
    xp[0] = pack_split(x4.x); xp[1] = pack_split(x4.y);
    xp[2] = pack_split(x4.z); xp[3] = pack_split(x4.w);
    unsigned* zp = Xs + (16 + cp) * 65 + nq * 4;
    zp[0] = 0u; zp[1] = 0u; zp[2] = 0u; zp[3] = 0u;
    __syncthreads();

    // layer 1: wave w -> mid-feats 16w..16w+15
    {
        const ushort* wp = wf + lane * 8;
        const bf16x8 wh = *(const bf16x8*)(wp + (w * 2) * 512);
        const bf16x8 wl = *(const bf16x8*)(wp + (w * 2 + 1) * 512);
#pragma unroll
        for (int nt = 0; nt < 4; nt++) {
            const unsigned* bp = Xs + (quad * 8) * 65 + nt * 16 + nl;
            bf16x8 bh, bl; frag_packed(bp, bh, bl);
            f32x4 c = {0.f, 0.f, 0.f, 0.f};
            c = MFMA(wh, bh, c); c = MFMA(wh, bl, c); c = MFMA(wl, bh, c);
#pragma unroll
            for (int reg = 0; reg < 4; reg++) {
                const int fm = 16 * w + quad * 4 + reg;
                Hs[fm * 65 + nt * 16 + nl] = pack_split(fmaxf(c[reg] + e1b[fm], 0.f));
            }
        }
    }
    __syncthreads();

    // layer 2: K=64 (2 kc)
    const ushort* e2f = wf + 4096;
    f32x4 a2[4];
#pragma unroll
    for (int nt = 0; nt < 4; nt++) a2[nt] = (f32x4){0.f, 0.f, 0.f, 0.f};
#pragma unroll
    for (int kc = 0; kc < 2; kc++) {
        const ushort* wp = e2f + lane * 8;
        const bf16x8 wh = *(const bf16x8*)(wp + ((kc * 4 + w) * 2) * 512);
        const bf16x8 wl = *(const bf16x8*)(wp + ((kc * 4 + w) * 2 + 1) * 512);
#pragma unroll
        for (int nt = 0; nt < 4; nt++) {
            const unsigned* bp = Hs + (kc * 32 + quad * 8) * 65 + nt * 16 + nl;
            bf16x8 bh, bl; frag_packed(bp, bh, bl);
            a2[nt] = MFMA(wh, bh, a2[nt]);
            a2[nt] = MFMA(wh, bl, a2[nt]);
            a2[nt] = MFMA(wl, bh, a2[nt]);
        }
    }
#pragma unroll
    for (int reg = 0; reg < 4; reg++) {
        const int f = 16 * w + quad * 4 + reg;
        const float bv = e2b[f];
#pragma unroll
        for (int nt = 0; nt < 4; nt++)
            h0[((size_t)(b * 64 + f) << 12) + row * 64 + nt * 16 + nl] =
                fmaxf(a2[nt][reg] + bv, 0.f);
    }
}

// ---- GNN layer: block = (b, row); rolling staging pipeline, packed LDS ----
template <int K, bool MEAN>
__global__ __launch_bounds__(256, 4) void gnn_kernel(
    const float* __restrict__ hin, const ushort* __restrict__ wf,
    const float* __restrict__ bias, float* __restrict__ hout,
    float* __restrict__ gsum)
{
    constexpr int NH = K / 64;            // 64-plane halves
    __shared__ unsigned As[NH][64 * 65];  // packed hi|lo
    const int tid = threadIdx.x;
    // XCD-contiguous remap: each XCD (blk%8) owns 128 consecutive (b,row) ids
    const int bid = ((blockIdx.x & 7) << 7) | (blockIdx.x >> 3);
    const int b = bid >> 6, row = bid & 63;
    const int lane = tid & 63, w = tid >> 6, quad = lane >> 4, nl = lane & 15;
    const int kp = tid >> 4, nq = tid & 15;
    const float* hb = hin + (size_t)b * K * 4096;
    const int rowu = (row > 0) ? row - 1 : row;
    const int rowd = (row < 63) ? row + 1 : row;
    const float su = (row > 0) ? 1.f : 0.f;
    const float sd = (row < 63) ? 1.f : 0.f;
    float inv[4];
#pragma unroll
    for (int i = 0; i < 4; i++) {
        const int n = nq * 4 + i;
        const int deg = (row > 0) + (row < 63) + (n > 0) + (n < 63);
        inv[i] = 1.f / ((float)deg + 1e-6f);
    }

    f32x4 acc[4][2];
#pragma unroll
    for (int nt = 0; nt < 4; nt++) {
        acc[nt][0] = (f32x4){0.f, 0.f, 0.f, 0.f};
        acc[nt][1] = (f32x4){0.f, 0.f, 0.f, 0.f};
    }

    auto load_group = [&](int kh, int it, float4& c, float4& u, float4& d) {
        const int kk = it * 16 + kp;
        const float* pk = hb + ((size_t)(kh * 64 + kk) << 12) + nq * 4;
        c = *(const float4*)(pk + row * 64);
        u = *(const float4*)(pk + rowu * 64);
        d = *(const float4*)(pk + rowd * 64);
    };
    auto stage_group = [&](int kh, int it, const float4& c, const float4& u, const float4& d) {
        const int kk = it * 16 + kp;
        const float pw = __shfl_up(c.w, 1);
        const float nx = __shfl_down(c.x, 1);
        const float lx = (nq > 0) ? pw : 0.f;
        const float rw = (nq < 15) ? nx : 0.f;
        unsigned* ap = As[kh] + kk * 65 + nq * 4;
        ap[0] = pack_split((su * u.x + sd * d.x + lx + c.y) * inv[0]);
        ap[1] = pack_split((su * u.y + sd * d.y + c.x + c.z) * inv[1]);
        ap[2] = pack_split((su * u.z + sd * d.z + c.y + c.w) * inv[2]);
        ap[3] = pack_split((su * u.w + sd * d.w + c.z + rw) * inv[3]);
    };
    // rolling 2-slot pipeline: <=6 float4 live, ~6 loads in flight
    auto load_stage_half = [&](int kh) {
        float4 c0, u0, d0, c1, u1, d1;
        load_group(kh, 0, c0, u0, d0);
        load_group(kh, 1, c1, u1, d1);
        stage_group(kh, 0, c0, u0, d0);
        load_group(kh, 2, c0, u0, d0);
        stage_group(kh, 1, c1, u1, d1);
        load_group(kh, 3, c1, u1, d1);
        stage_group(kh, 2, c0, u0, d0);
        stage_group(kh, 3, c1, u1, d1);
    };
    auto consume = [&](int kh) {
        const unsigned* src = As[kh];
#pragma unroll
        for (int kc = 0; kc < 2; kc++) {
            const int kcg = kh * 2 + kc;
            const ushort* wp = wf + lane * 8;
            const bf16x8 wh0 = *(const bf16x8*)(wp + ((kcg * 8 + 2 * w)     * 2)     * 512);
            const bf16x8 wl0 = *(const bf16x8*)(wp + ((kcg * 8 + 2 * w)     * 2 + 1) * 512);
            const bf16x8 wh1 = *(const bf16x8*)(wp + ((kcg * 8 + 2 * w + 1) * 2)     * 512);
            const bf16x8 wl1 = *(const bf16x8*)(wp + ((kcg * 8 + 2 * w + 1) * 2 + 1) * 512);
#pragma unroll
            for (int nt = 0; nt < 4; nt++) {
                const unsigned* bp = src + (kc * 32 + quad * 8) * 65 + nt * 16 + nl;
                bf16x8 bh, bl; frag_packed(bp, bh, bl);
                acc[nt][0] = MFMA(wh0, bh, acc[nt][0]);
                acc[nt][0] = MFMA(wh0, bl, acc[nt][0]);
                acc[nt][0] = MFMA(wl0, bh, acc[nt][0]);
                acc[nt][1] = MFMA(wh1, bh, acc[nt][1]);
                acc[nt][1] = MFMA(wh1, bl, acc[nt][1]);
                acc[nt][1] = MFMA(wl1, bh, acc[nt][1]);
            }
        }
    };

    load_stage_half(0);
    __syncthreads();
#pragma unroll
    for (int kh = 0; kh < NH; kh++) {
        if (kh + 1 < NH) load_stage_half(kh + 1);   // writes buf kh+1 (dbuf-safe)
        consume(kh);
        if (kh + 1 < NH) __syncthreads();
    }

    // ---- epilogue: + rowsum*bias, relu ----
    if (!MEAN) {
#pragma unroll
        for (int ftl = 0; ftl < 2; ftl++) {
            const int fb = 32 * w + 16 * ftl + quad * 4;
            const float b0 = bias[fb], b1 = bias[fb + 1], b2 = bias[fb + 2], b3 = bias[fb + 3];
#pragma unroll
            for (int nt = 0; nt < 4; nt++) {
                const int n = 16 * nt + nl;
                const int deg = (row > 0) + (row < 63) + (n > 0) + (n < 63);
                const float rs = (float)deg / ((float)deg + 1e-6f);
                float* op = hout + ((size_t)(b * 128 + fb) << 12) + row * 64 + n;
                op[0]        = fmaxf(acc[nt][ftl][0] + rs * b0, 0.f);
                op[1u << 12] = fmaxf(acc[nt][ftl][1] + rs * b1, 0.f);
                op[2u << 12] = fmaxf(acc[nt][ftl][2] + rs * b2, 0.f);
                op[3u << 12] = fmaxf(acc[nt][ftl][3] + rs * b3, 0.f);
            }
        }
    } else {
#pragma unroll
        for (int ftl = 0; ftl < 2; ftl++) {
            const int fb = 32 * w + 16 * ftl + quad * 4;
#pragma unroll
            for (int reg = 0; reg < 4; reg++) {
                const float bv = bias[fb + reg];
                float v = 0.f;
#pragma unroll
                for (int nt = 0; nt < 4; nt++) {
                    const int n = 16 * nt + nl;
                    const int deg = (row > 0) + (row < 63) + (n > 0) + (n < 63);
                    const float rs = (float)deg / ((float)deg + 1e-6f);
                    v += fmaxf(acc[nt][ftl][reg] + rs * bv, 0.f);
                }
                v += __shfl_xor(v, 1); v += __shfl_xor(v, 2);
                v += __shfl_xor(v, 4); v += __shfl_xor(v, 8);
                if (nl == 0) atomicAdd(&gsum[b * 128 + fb + reg], v * (1.f / 4096.f));
            }
        }
    }
}

// ---- readout: per-batch block, 2-layer MLP (fp32 vector) ----
__global__ __launch_bounds__(256) void readout_kernel(
    const float* __restrict__ gsum, const float* __restrict__ r1w,
    const float* __restrict__ r1b, const float* __restrict__ r2w,
    const float* __restrict__ r2b, float* __restrict__ out)
{
    __shared__ float gs[128];
    __shared__ float g2[256];
    const int b = blockIdx.x, tid = threadIdx.x;
    if (tid < 128) gs[tid] = gsum[b * 128 + tid];
    __syncthreads();
    float a = r1b[tid];
#pragma unroll 16
    for (int k = 0; k < 128; k++) a = fmaf(gs[k], r1w[k * 256 + tid], a);
    g2[tid] = fmaxf(a, 0.f);
    __syncthreads();
    float a2 = r2b[tid];
#pragma unroll 16
    for (int k = 0; k < 256; k++) a2 = fmaf(g2[k], r2w[k * 256 + tid], a2);
    out[b * 256 + tid] = fmaxf(a2, 0.f);
}

extern "C" void kernel_launch(void* const* d_in, const int* in_sizes, int n_in,
                              void* d_out, int out_size, void* d_ws, size_t ws_size,
                              hipStream_t stream)
{
    const float* obs = (const float*)d_in[0];
    const float* e1w = (const float*)d_in[1];
    const float* e1b = (const float*)d_in[2];
    const float* e2w = (const float*)d_in[3];
    const float* e2b = (const float*)d_in[4];
    const float* g1w = (const float*)d_in[5];
    const float* g1b = (const float*)d_in[6];
    const float* g2w = (const float*)d_in[7];
    const float* g2b = (const float*)d_in[8];
    const float* g3w = (const float*)d_in[9];
    const float* g3b = (const float*)d_in[10];
    const float* r1w = (const float*)d_in[11];
    const float* r1b = (const float*)d_in[12];
    const float* r2w = (const float*)d_in[13];
    const float* r2b = (const float*)d_in[14];
    float* out = (float*)d_out;
    float* ws = (float*)d_ws;

    float* h0 = ws;                                   // 16 MB
    float* h1 = ws + 4194304;                         // 32 MB
    float* h2 = ws + 4194304 + 8388608;               // 32 MB
    float* gsum = (float*)((char*)d_ws + 80u * 1024u * 1024u);          // 8 KB
    ushort* wfb = (ushort*)((char*)d_ws + 80u * 1024u * 1024u + 8192u); // 184 KB

    hipLaunchKernelGGL(wprep_kernel, dim3(124), dim3(64), 0, stream,
                       e1w, e2w, g1w, g2w, g3w, wfb, gsum);
    hipLaunchKernelGGL(embed_kernel, dim3(1024), dim3(256), 0, stream,
                       obs, wfb, e1b, e2b, h0);
    hipLaunchKernelGGL((gnn_kernel<64, false>), dim3(1024), dim3(256), 0, stream,
                       h0, wfb + 12288, g1b, h1, nullptr);
    hipLaunchKernelGGL((gnn_kernel<128, false>), dim3(1024), dim3(256), 0, stream,
                       h1, wfb + 28672, g2b, h2, nullptr);
    hipLaunchKernelGGL((gnn_kernel<128, true>), dim3(1024), dim3(256), 0, stream,
                       h2, wfb + 61440, g3b, nullptr, gsum);
    hipLaunchKernelGGL(readout_kernel, dim3(16), dim3(256), 0, stream,
                       gsum, r1w, r1b, r2w, r2b, out);
}